// Round 8
// baseline (176.083 us; speedup 1.0000x reference)
//
#include <hip/hip_runtime.h>
#include <math.h>

// B=4, T=48, W=8, H=8, C=32; d_ff=64; periods {2,3,4}. T%P==0 always.
// (1x1 + 3^4)/2 inception folded into one 81-tap conv (center tap 40).
// Padded in L,P,W,H -> branch-free 81 taps.
// R8: single-wave blocks (1152), per-wave double-buffered global_load_lds
// staging with fine-grained s_waitcnt vmcnt(N) (no barriers), o-split waves,
// constexpr-divisor prep.

typedef __attribute__((ext_vector_type(8))) short bf16x8;
typedef __attribute__((ext_vector_type(4))) float f32x4;
typedef unsigned short u16;

#define XB0 0
#define XB1 1331200            // 4 * 26*4*3200
#define XB2 2483200            // XB1 + 4 * 18*5*3200
#define XTOT 3558400           // XB2 + 4 * 14*6*3200
#define W1OFF XTOT             // 165888 bf16: [half][grp][tapig][chunk*8+j]
#define W2OFF (XTOT + 165888)  // 165888 bf16: [oh][grp][tapig][chunk*8+j]
#define H1OFF (XTOT + 331776)  // h1pad3 (C=64, swizzled cells)
#define HB0 0
#define HB1 2662400            // 4 * 26*4*6400
#define HB2 4966400            // HB1 + 4 * 18*5*6400
#define H1TOT 7116800
#define H2OFF_U16 (H1OFF + H1TOT)
#define H2_PER 393216          // fp32 per period: 192*64*32
#define PREP_N (XTOT + 331776)

__device__ __forceinline__ u16 f2bf(float f) {
    unsigned u = __float_as_uint(f);
    unsigned r = u + 0x7fffu + ((u >> 16) & 1u);
    return (u16)(r >> 16);
}
__device__ __forceinline__ float gelu_exact(float v) {
    return 0.5f * v * (1.0f + erff(v * 0.7071067811865476f));
}

// async copy of 1 KB: 64 lanes x 16 B. LDS dest = wave-uniform base + lane*16.
__device__ __forceinline__ void cp1k(const u16* g, u16* l, int lane) {
    __builtin_amdgcn_global_load_lds(
        (const __attribute__((address_space(1))) unsigned int*)(g + lane * 8),
        (__attribute__((address_space(3))) unsigned int*)(l + lane * 8),
        16, 0, 0);
}

// ---- prep (constexpr divisors everywhere) ----
// xpad cell (10x10x32): addr = cellpos*32 + sc*8 + (c&7), sc=(c>>3)^(cellpos&3)
template<int P>
__device__ __forceinline__ void prep_x(const float* __restrict__ x,
                                       u16* __restrict__ dst, int j) {
    constexpr int L = 48 / P;
    constexpr int SZ = (L + 2) * (P + 2) * 3200;
    int b = j / SZ; int r = j - b * SZ;
    int cell2d = r / 3200; int inner = r - cell2d * 3200;
    int cellpos = inner >> 5; int low = inner & 31;
    int sc = low >> 3, jj = low & 7;
    int c = ((sc ^ (cellpos & 3)) << 3) + jj;
    int wp = cellpos / 10, hp = cellpos - (cellpos / 10) * 10;
    int qp = cell2d % (P + 2), lp = cell2d / (P + 2);
    float v = 0.f;
    if (lp >= 1 && lp <= L && qp >= 1 && qp <= P &&
        wp >= 1 && wp <= 8 && hp >= 1 && hp <= 8) {
        int t = (lp - 1) * P + (qp - 1);
        v = x[((b * 48 + t) * 64 + (wp - 1) * 8 + (hp - 1)) * 32 + c];
    }
    dst[j] = f2bf(v);
}

__global__ __launch_bounds__(256) void prep(
    const float* __restrict__ x,
    const float* __restrict__ w1_0, const float* __restrict__ w1_1,
    const float* __restrict__ w2_0, const float* __restrict__ w2_1,
    u16* __restrict__ ws) {
    int i = blockIdx.x * 256 + threadIdx.x;
    if (i < XB1) {
        prep_x<2>(x, ws + XB0, i - XB0);
    } else if (i < XB2) {
        prep_x<3>(x, ws + XB1, i - XB1);
    } else if (i < XTOT) {
        prep_x<4>(x, ws + XB2, i - XB2);
    } else if (i < W2OFF) {
        // w1b: [half(2)][grp(9)][tapig(9)][chunk(128)*8+jj]
        // chunk = (quad*2+nt)*16+m -> o = half*32+nt*16+m, c = quad*8+jj
        int j = i - W1OFF;
        int half = j / 82944; int r = j - half * 82944;
        int grp = r / 9216; int r2 = r - grp * 9216;
        int tapig = r2 >> 10; int r3 = r2 & 1023;
        int chunk = r3 >> 3, jj = r3 & 7;
        int m = chunk & 15, k = chunk >> 4;
        int nt = k & 1, quad = k >> 1;
        int o = half * 32 + nt * 16 + m, c = quad * 8 + jj;
        int tap = grp * 9 + tapig;
        float v = 0.5f * w1_1[(o * 32 + c) * 81 + tap];
        if (tap == 40) v += 0.5f * w1_0[o * 32 + c];
        ws[i] = f2bf(v);
    } else if (i < PREP_N) {
        // w2b: [oh(2)][grp(9)][tapig(9)][chunk(128)*8+jj]
        // chunk = (ks*4+quad)*16+m -> o = oh*16+m, c = ks*32+quad*8+jj
        int j = i - W2OFF;
        int oh = j / 82944; int r = j - oh * 82944;
        int grp = r / 9216; int r2 = r - grp * 9216;
        int tapig = r2 >> 10; int r3 = r2 & 1023;
        int chunk = r3 >> 3, jj = r3 & 7;
        int m = chunk & 15, k = chunk >> 4;
        int quad = k & 3, ks = k >> 2;
        int o = oh * 16 + m, c = ks * 32 + quad * 8 + jj;
        int tap = grp * 9 + tapig;
        float v = 0.5f * w2_1[(o * 64 + c) * 81 + tap];
        if (tap == 40) v += 0.5f * w2_0[o * 64 + c];
        ws[i] = f2bf(v);
    }
}

// ---- conv1 (C32->C64) + GELU. 1 wave = one t, one 32-o half. ----
// LDS buffer: w 9216 u16 (9 taps x 32o x 32c) + act 3584 u16 (cell+slack)
template<int P>
__device__ __forceinline__ void conv1_body(
    const u16* __restrict__ xpad, const u16* __restrict__ w1b,
    u16* __restrict__ h1pad, int half, int bt,
    u16* __restrict__ sb0, u16* __restrict__ sb1) {
    constexpr int L = 48 / P;
    constexpr int XB = (P == 2) ? XB0 : (P == 3) ? XB1 : XB2;
    constexpr int HB = (P == 2) ? HB0 : (P == 3) ? HB1 : HB2;
    constexpr int XSTR = (L + 2) * (P + 2) * 3200;
    constexpr int HSTR = (L + 2) * (P + 2) * 6400;

    int lane = threadIdx.x;
    int m = lane & 15, quad = lane >> 4;
    int b = bt / 48, t = bt - b * 48;
    int l = t / P, q = t - l * P;

    const u16* xcell0 = xpad + XB + b * XSTR + (l * (P + 2) + q) * 3200;
    const u16* wsrc_base = w1b + half * 82944;
    u16* sb[2] = {sb0, sb1};

    int sp[4];
#pragma unroll
    for (int mt = 0; mt < 4; ++mt) {
        int pos = mt * 16 + m;
        sp[mt] = (pos >> 3) * 10 + (pos & 7);   // base cellpos (w*10+h)
    }

    f32x4 acc[4][2];
#pragma unroll
    for (int mt = 0; mt < 4; ++mt)
#pragma unroll
        for (int nt = 0; nt < 2; ++nt) acc[mt][nt] = f32x4{0.f, 0.f, 0.f, 0.f};

    // stage group 0
    {
        const u16* wsp = wsrc_base;
#pragma unroll
        for (int i = 0; i < 18; ++i) cp1k(wsp + i * 512, sb0 + i * 512, lane);
        const u16* asp = xcell0;    // dl=0,dq=0
#pragma unroll
        for (int i = 0; i < 7; ++i) cp1k(asp + i * 512, sb0 + 9216 + i * 512, lane);
    }

#pragma unroll 1
    for (int g = 0; g < 9; ++g) {
        asm volatile("s_waitcnt lgkmcnt(0)" ::: "memory");
        if (g < 8) {
            int gn = g + 1;
            int dl = gn / 3, dq = gn - (gn / 3) * 3;
            u16* buf = sb[gn & 1];
            const u16* wsp = wsrc_base + gn * 9216;
#pragma unroll
            for (int i = 0; i < 18; ++i) cp1k(wsp + i * 512, buf + i * 512, lane);
            const u16* asp = xcell0 + (dl * (P + 2) + dq) * 3200;
#pragma unroll
            for (int i = 0; i < 7; ++i) cp1k(asp + i * 512, buf + 9216 + i * 512, lane);
            asm volatile("s_waitcnt vmcnt(25)" ::: "memory");
        } else {
            asm volatile("s_waitcnt vmcnt(0)" ::: "memory");
        }
        const u16* bw = sb[g & 1];
        const u16* ba = bw + 9216;
#pragma unroll
        for (int dwh = 0; dwh < 9; ++dwh) {
            int dw = dwh / 3, dh = dwh - (dwh / 3) * 3;
            bf16x8 wf[2];
#pragma unroll
            for (int nt = 0; nt < 2; ++nt)
                wf[nt] = *(const bf16x8*)(bw + dwh * 1024 +
                                          (((quad * 2 + nt) * 16 + m) << 3));
            bf16x8 af[4];
#pragma unroll
            for (int mt = 0; mt < 4; ++mt) {
                int cellpos = sp[mt] + dw * 10 + dh;
                af[mt] = *(const bf16x8*)(ba + cellpos * 32 +
                                          ((quad ^ (cellpos & 3)) << 3));
            }
#pragma unroll
            for (int mt = 0; mt < 4; ++mt)
#pragma unroll
                for (int nt = 0; nt < 2; ++nt)
                    acc[mt][nt] = __builtin_amdgcn_mfma_f32_16x16x32_bf16(
                        af[mt], wf[nt], acc[mt][nt], 0, 0, 0);
        }
    }

    // epilogue: GELU -> bf16 -> swizzled h1pad cell (interior)
    u16* hcell = h1pad + HB + b * HSTR + ((l + 1) * (P + 2) + (q + 1)) * 6400;
#pragma unroll
    for (int mt = 0; mt < 4; ++mt)
#pragma unroll
        for (int r = 0; r < 4; ++r) {
            int pos = mt * 16 + quad * 4 + r;
            int cellpos = ((pos >> 3) + 1) * 10 + (pos & 7) + 1;
#pragma unroll
            for (int nt = 0; nt < 2; ++nt) {
                int o = half * 32 + nt * 16 + m;
                hcell[cellpos * 64 + (((o >> 3) ^ (cellpos & 7)) << 3) + (o & 7)] =
                    f2bf(gelu_exact(acc[mt][nt][r]));
            }
        }
}

__global__ __launch_bounds__(64) void conv1_k(
    const u16* __restrict__ ws_x, const u16* __restrict__ ws_w1,
    u16* __restrict__ ws_h1) {
    __shared__ __align__(16) u16 s_lds[2][12800];   // 51.2 KB -> 3 blocks/CU
    int g = blockIdx.x;
    int jid = (g & 7) * 144 + (g >> 3);             // XCD-chunked, 1152 = 8*144
    int per = jid / 384; int rem = jid - per * 384;
    int half = rem / 192; int bt = rem - half * 192;
    if (per == 0)      conv1_body<2>(ws_x, ws_w1, ws_h1, half, bt, s_lds[0], s_lds[1]);
    else if (per == 1) conv1_body<3>(ws_x, ws_w1, ws_h1, half, bt, s_lds[0], s_lds[1]);
    else               conv1_body<4>(ws_x, ws_w1, ws_h1, half, bt, s_lds[0], s_lds[1]);
}

// ---- conv2 (C64->C32). 1 wave = one t, one 16-o half, K=64. ----
// LDS buffer: w 9216 u16 (9 taps x 16o x 64c) + act 6656 u16 (cell+slack)
template<int P>
__device__ __forceinline__ void conv2_body(
    const u16* __restrict__ h1pad, const u16* __restrict__ w2b,
    float* __restrict__ h2per, int oh, int bt,
    u16* __restrict__ sb0, u16* __restrict__ sb1) {
    constexpr int L = 48 / P;
    constexpr int HB = (P == 2) ? HB0 : (P == 3) ? HB1 : HB2;
    constexpr int HSTR = (L + 2) * (P + 2) * 6400;

    int lane = threadIdx.x;
    int m = lane & 15, quad = lane >> 4;
    int b = bt / 48, t = bt - b * 48;
    int l = t / P, q = t - l * P;

    const u16* hcell0 = h1pad + HB + b * HSTR + (l * (P + 2) + q) * 6400;
    const u16* wsrc_base = w2b + oh * 82944;
    u16* sb[2] = {sb0, sb1};

    int sp[4];
#pragma unroll
    for (int mt = 0; mt < 4; ++mt) {
        int pos = mt * 16 + m;
        sp[mt] = (pos >> 3) * 10 + (pos & 7);
    }

    f32x4 acc[4];
#pragma unroll
    for (int mt = 0; mt < 4; ++mt) acc[mt] = f32x4{0.f, 0.f, 0.f, 0.f};

    {
        const u16* wsp = wsrc_base;
#pragma unroll
        for (int i = 0; i < 18; ++i) cp1k(wsp + i * 512, sb0 + i * 512, lane);
        const u16* asp = hcell0;
#pragma unroll
        for (int i = 0; i < 13; ++i) cp1k(asp + i * 512, sb0 + 9216 + i * 512, lane);
    }

#pragma unroll 1
    for (int g = 0; g < 9; ++g) {
        asm volatile("s_waitcnt lgkmcnt(0)" ::: "memory");
        if (g < 8) {
            int gn = g + 1;
            int dl = gn / 3, dq = gn - (gn / 3) * 3;
            u16* buf = sb[gn & 1];
            const u16* wsp = wsrc_base + gn * 9216;
#pragma unroll
            for (int i = 0; i < 18; ++i) cp1k(wsp + i * 512, buf + i * 512, lane);
            const u16* asp = hcell0 + (dl * (P + 2) + dq) * 6400;
#pragma unroll
            for (int i = 0; i < 13; ++i) cp1k(asp + i * 512, buf + 9216 + i * 512, lane);
            asm volatile("s_waitcnt vmcnt(31)" ::: "memory");
        } else {
            asm volatile("s_waitcnt vmcnt(0)" ::: "memory");
        }
        const u16* bw = sb[g & 1];
        const u16* ba = bw + 9216;
#pragma unroll
        for (int dwh = 0; dwh < 9; ++dwh) {
            int dw = dwh / 3, dh = dwh - (dwh / 3) * 3;
            bf16x8 wf[2];   // [ks]
#pragma unroll
            for (int ks = 0; ks < 2; ++ks)
                wf[ks] = *(const bf16x8*)(bw + dwh * 1024 +
                                          (((ks * 4 + quad) * 16 + m) << 3));
            bf16x8 af[4][2];   // [mt][ks]
#pragma unroll
            for (int mt = 0; mt < 4; ++mt) {
                int cellpos = sp[mt] + dw * 10 + dh;
#pragma unroll
                for (int ks = 0; ks < 2; ++ks)
                    af[mt][ks] = *(const bf16x8*)(ba + cellpos * 64 +
                        (((ks * 4 + quad) ^ (cellpos & 7)) << 3));
            }
#pragma unroll
            for (int mt = 0; mt < 4; ++mt)
#pragma unroll
                for (int ks = 0; ks < 2; ++ks)
                    acc[mt] = __builtin_amdgcn_mfma_f32_16x16x32_bf16(
                        af[mt][ks], wf[ks], acc[mt], 0, 0, 0);
        }
    }

    float* orow = h2per + (b * 48 + t) * 2048;
#pragma unroll
    for (int mt = 0; mt < 4; ++mt)
#pragma unroll
        for (int r = 0; r < 4; ++r) {
            int pos = mt * 16 + quad * 4 + r;
            orow[pos * 32 + oh * 16 + m] = acc[mt][r];
        }
}

__global__ __launch_bounds__(64) void conv2_k(
    const u16* __restrict__ ws_h1, const u16* __restrict__ ws_w2,
    float* __restrict__ h2) {
    __shared__ __align__(16) u16 s_lds[2][15872];   // 63.5 KB -> 2 blocks/CU
    int g = blockIdx.x;
    int jid = (g & 7) * 144 + (g >> 3);             // same XCD mapping as conv1
    int per = jid / 384; int rem = jid - per * 384;
    int oh = rem / 192; int bt = rem - oh * 192;
    float* h2per = h2 + per * H2_PER;
    if (per == 0)      conv2_body<2>(ws_h1, ws_w2, h2per, oh, bt, s_lds[0], s_lds[1]);
    else if (per == 1) conv2_body<3>(ws_h1, ws_w2, h2per, oh, bt, s_lds[0], s_lds[1]);
    else               conv2_body<4>(ws_h1, ws_w2, h2per, oh, bt, s_lds[0], s_lds[1]);
}

// ---- out = x + (h2_p0 + h2_p1 + h2_p2) / 3 ----
__global__ __launch_bounds__(256) void final_add(
    const float* __restrict__ x, const float* __restrict__ h2,
    float* __restrict__ out) {
    int i = blockIdx.x * 256 + threadIdx.x;
    float4 xv = ((const float4*)x)[i];
    float4 a = ((const float4*)h2)[i];
    float4 bv = ((const float4*)(h2 + H2_PER))[i];
    float4 cv = ((const float4*)(h2 + 2 * H2_PER))[i];
    const float s = 1.0f / 3.0f;
    float4 o;
    o.x = xv.x + (a.x + bv.x + cv.x) * s;
    o.y = xv.y + (a.y + bv.y + cv.y) * s;
    o.z = xv.z + (a.z + bv.z + cv.z) * s;
    o.w = xv.w + (a.w + bv.w + cv.w) * s;
    ((float4*)out)[i] = o;
}

extern "C" void kernel_launch(void* const* d_in, const int* in_sizes, int n_in,
                              void* d_out, int out_size, void* d_ws, size_t ws_size,
                              hipStream_t stream) {
    const float* x    = (const float*)d_in[0];
    const float* w1_0 = (const float*)d_in[1];
    const float* w1_1 = (const float*)d_in[2];
    const float* w2_0 = (const float*)d_in[3];
    const float* w2_1 = (const float*)d_in[4];
    float* out = (float*)d_out;

    u16* ws = (u16*)d_ws;
    u16* ws_x  = ws;
    u16* ws_w1 = ws + W1OFF;
    u16* ws_w2 = ws + W2OFF;
    u16* ws_h1 = ws + H1OFF;
    float* h2  = (float*)(ws + H2OFF_U16);

    (void)hipMemsetAsync(ws_h1, 0, (size_t)H1TOT * 2, stream);
    prep<<<PREP_N / 256, 256, 0, stream>>>(x, w1_0, w1_1, w2_0, w2_1, ws);
    conv1_k<<<1152, 64, 0, stream>>>(ws_x, ws_w1, ws_h1);
    conv2_k<<<1152, 64, 0, stream>>>(ws_h1, ws_w2, h2);
    final_add<<<H2_PER / 4 / 256, 256, 0, stream>>>(x, h2, out);
}

// Round 9
// 167.000 us; speedup vs baseline: 1.0544x; 1.0544x over previous
//
#include <hip/hip_runtime.h>
#include <math.h>

// B=4, T=48, W=8, H=8, C=32; d_ff=64; periods {2,3,4}. T%P==0 always.
// (1x1 + 3^4)/2 inception folded into one 81-tap conv (center tap 40).
// Padded in L,P,W,H -> branch-free 81 taps.
// R9: barrier-free per-wave staging with TAP-granular pipelining:
// 4-deep per-tap weight ring (4 KB/tap) + double-buffered act cells in LDS,
// exact in-order vmcnt constants (never drain more than ~3 taps ahead).
// Wave = one t, all output channels. 576 waves per conv kernel.

typedef __attribute__((ext_vector_type(8))) short bf16x8;
typedef __attribute__((ext_vector_type(4))) float f32x4;
typedef unsigned short u16;

#define XB0 0
#define XB1 1331200            // 4 * 26*4*3200
#define XB2 2483200            // XB1 + 4 * 18*5*3200
#define XTOT 3558400           // XB2 + 4 * 14*6*3200
#define W1OFF XTOT             // 165888 bf16: [tap 0..80][2048]  (R7 layout)
#define W2OFF (XTOT + 165888)  // 165888 bf16: [tap 0..80][2048]  (R7 layout)
#define H1OFF (XTOT + 331776)  // h1pad3 (C=64, swizzled cells)
#define HB0 0
#define HB1 2662400            // 4 * 26*4*6400
#define HB2 4966400            // HB1 + 4 * 18*5*6400
#define H1TOT 7116800
#define H2OFF_U16 (H1OFF + H1TOT)
#define H2_PER 393216          // fp32 per period: 192*64*32
#define PREP_N (XTOT + 331776)

#define WAITVM(N) asm volatile("s_waitcnt vmcnt(" #N ")" ::: "memory")

__device__ __forceinline__ u16 f2bf(float f) {
    unsigned u = __float_as_uint(f);
    unsigned r = u + 0x7fffu + ((u >> 16) & 1u);
    return (u16)(r >> 16);
}
__device__ __forceinline__ float gelu_exact(float v) {
    return 0.5f * v * (1.0f + erff(v * 0.7071067811865476f));
}

// async copy of 1 KB: 64 lanes x 16 B. LDS dest = wave-uniform base + lane*16.
__device__ __forceinline__ void cp1k(const u16* g, u16* l, int lane) {
    __builtin_amdgcn_global_load_lds(
        (const __attribute__((address_space(1))) unsigned int*)(g + lane * 8),
        (__attribute__((address_space(3))) unsigned int*)(l + lane * 8),
        16, 0, 0);
}

// ---- prep ----
// xpad cell (10x10x32): addr = cellpos*32 + sc*8 + (c&7), sc=(c>>3)^(cellpos&3)
template<int P>
__device__ __forceinline__ void prep_x(const float* __restrict__ x,
                                       u16* __restrict__ dst, int j) {
    constexpr int L = 48 / P;
    constexpr int SZ = (L + 2) * (P + 2) * 3200;
    int b = j / SZ; int r = j - b * SZ;
    int cell2d = r / 3200; int inner = r - cell2d * 3200;
    int cellpos = inner >> 5; int low = inner & 31;
    int sc = low >> 3, jj = low & 7;
    int c = ((sc ^ (cellpos & 3)) << 3) + jj;
    int wp = cellpos / 10, hp = cellpos - (cellpos / 10) * 10;
    int qp = cell2d % (P + 2), lp = cell2d / (P + 2);
    float v = 0.f;
    if (lp >= 1 && lp <= L && qp >= 1 && qp <= P &&
        wp >= 1 && wp <= 8 && hp >= 1 && hp <= 8) {
        int t = (lp - 1) * P + (qp - 1);
        v = x[((b * 48 + t) * 64 + (wp - 1) * 8 + (hp - 1)) * 32 + c];
    }
    dst[j] = f2bf(v);
}

__global__ __launch_bounds__(256) void prep(
    const float* __restrict__ x,
    const float* __restrict__ w1_0, const float* __restrict__ w1_1,
    const float* __restrict__ w2_0, const float* __restrict__ w2_1,
    u16* __restrict__ ws) {
    int i = blockIdx.x * 256 + threadIdx.x;
    if (i < XB1) {
        prep_x<2>(x, ws + XB0, i - XB0);
    } else if (i < XB2) {
        prep_x<3>(x, ws + XB1, i - XB1);
    } else if (i < XTOT) {
        prep_x<4>(x, ws + XB2, i - XB2);
    } else if (i < W2OFF) {
        // w1: [tap][chunk(256)*8+jj], chunk = (quad*4+nt)*16+m
        int j = i - W1OFF;
        int tap = j >> 11; int r = j & 2047;
        int chunk = r >> 3, jj = r & 7;
        int m = chunk & 15, nt = (chunk >> 4) & 3, quad = chunk >> 6;
        int o = nt * 16 + m, c = quad * 8 + jj;
        float v = 0.5f * w1_1[(o * 32 + c) * 81 + tap];
        if (tap == 40) v += 0.5f * w1_0[o * 32 + c];
        ws[i] = f2bf(v);
    } else if (i < PREP_N) {
        // w2: [tap][chunk(256)*8+jj], chunk = ((ks*4+quad)*2+nt)*16+m
        int j = i - W2OFF;
        int tap = j >> 11; int r = j & 2047;
        int chunk = r >> 3, jj = r & 7;
        int m = chunk & 15, nt = (chunk >> 4) & 1;
        int quad = (chunk >> 5) & 3, ks = chunk >> 7;
        int o = nt * 16 + m, c = ks * 32 + quad * 8 + jj;
        float v = 0.5f * w2_1[(o * 64 + c) * 81 + tap];
        if (tap == 40) v += 0.5f * w2_0[o * 64 + c];
        ws[i] = f2bf(v);
    }
}

// NOTE on tap order: linear tap Tt = g*9 + dwh, g = dl*3+dq. Ring slot =
// Tt & 3 (9 == 1 mod 4 -> consecutive taps rotate slots cleanly).

// ---- conv1 (C32->C64) + GELU. 1 wave = one t, all 64 o. ----
template<int P>
__device__ __forceinline__ void conv1_body(
    const u16* __restrict__ xpad, const u16* __restrict__ w1b,
    u16* __restrict__ h1pad, int bt,
    u16* __restrict__ s_w, u16* __restrict__ s_a) {
    constexpr int L = 48 / P;
    constexpr int XB = (P == 2) ? XB0 : (P == 3) ? XB1 : XB2;
    constexpr int HB = (P == 2) ? HB0 : (P == 3) ? HB1 : HB2;
    constexpr int XSTR = (L + 2) * (P + 2) * 3200;
    constexpr int HSTR = (L + 2) * (P + 2) * 6400;

    int lane = threadIdx.x;
    int m = lane & 15, quad = lane >> 4;
    int b = bt / 48, t = bt - b * 48;
    int l = t / P, q = t - l * P;

    const u16* xc = xpad + XB + b * XSTR + (l * (P + 2) + q) * 3200;

    int sp[4];
#pragma unroll
    for (int mt = 0; mt < 4; ++mt) {
        int pos = mt * 16 + m;
        sp[mt] = (pos >> 3) * 10 + (pos & 7);
    }

    f32x4 acc[4][4];
#pragma unroll
    for (int mt = 0; mt < 4; ++mt)
#pragma unroll
        for (int nt = 0; nt < 4; ++nt) acc[mt][nt] = f32x4{0.f, 0.f, 0.f, 0.f};

    // stage weight tap Tt (4 KB) into ring slot Tt&3
    auto issue_w = [&](int Tt) {
        const u16* src = w1b + Tt * 2048;
        u16* dst = s_w + (Tt & 3) * 2048;
#pragma unroll
        for (int i = 0; i < 4; ++i) cp1k(src + i * 512, dst + i * 512, lane);
    };
    // stage act cell for group gg into buffer gg&1 (7 KB, overread ok)
    auto issue_a = [&](int gg) {
        const u16* src = xc + ((gg / 3) * (P + 2) + (gg % 3)) * 3200;
        u16* dst = s_a + (gg & 1) * 3584;
#pragma unroll
        for (int i = 0; i < 7; ++i) cp1k(src + i * 512, dst + i * 512, lane);
    };
    // compute one tap: ring slot (runtime), dwh compile-time via unroll
    auto tapc = [&](int slot, int dwh, const u16* ba) {
        int dw = dwh / 3, dh = dwh - (dwh / 3) * 3;
        const u16* bw = s_w + slot * 2048;
        bf16x8 wf[4];
#pragma unroll
        for (int nt = 0; nt < 4; ++nt)
            wf[nt] = *(const bf16x8*)(bw + (((quad * 4 + nt) * 16 + m) << 3));
        bf16x8 af[4];
#pragma unroll
        for (int mt = 0; mt < 4; ++mt) {
            int cellpos = sp[mt] + dw * 10 + dh;
            af[mt] = *(const bf16x8*)(ba + cellpos * 32 +
                                      ((quad ^ (cellpos & 3)) << 3));
        }
#pragma unroll
        for (int mt = 0; mt < 4; ++mt)
#pragma unroll
            for (int nt = 0; nt < 4; ++nt)
                acc[mt][nt] = __builtin_amdgcn_mfma_f32_16x16x32_bf16(
                    af[mt], wf[nt], acc[mt][nt], 0, 0, 0);
    };

    // prologue: A[0], W taps 0..3
    issue_a(0);
    issue_w(0); issue_w(1); issue_w(2); issue_w(3);

#pragma unroll 1
    for (int g = 0; g < 8; ++g) {
        issue_a(g + 1);
        int T0 = g * 9;
        const u16* ba = s_a + (g & 1) * 3584;
        WAITVM(19); tapc((T0 + 0) & 3, 0, ba); issue_w(T0 + 4);
        WAITVM(19); tapc((T0 + 1) & 3, 1, ba); issue_w(T0 + 5);
        WAITVM(19); tapc((T0 + 2) & 3, 2, ba); issue_w(T0 + 6);
        WAITVM(19); tapc((T0 + 3) & 3, 3, ba); issue_w(T0 + 7);
        WAITVM(12); tapc((T0 + 4) & 3, 4, ba); issue_w(T0 + 8);
        WAITVM(12); tapc((T0 + 5) & 3, 5, ba); issue_w(T0 + 9);
        WAITVM(12); tapc((T0 + 6) & 3, 6, ba); issue_w(T0 + 10);
        WAITVM(12); tapc((T0 + 7) & 3, 7, ba); issue_w(T0 + 11);
        WAITVM(12); tapc((T0 + 8) & 3, 8, ba); issue_w(T0 + 12);
    }
    {   // tail group g=8 (taps 72..80; W[8][4..8]=76..80 issued at j=0..4)
        const u16* ba = s_a;   // 8&1 = 0
        WAITVM(12); tapc(72 & 3, 0, ba); issue_w(76);
        WAITVM(12); tapc(73 & 3, 1, ba); issue_w(77);
        WAITVM(12); tapc(74 & 3, 2, ba); issue_w(78);
        WAITVM(12); tapc(75 & 3, 3, ba); issue_w(79);
        WAITVM(12); tapc(76 & 3, 4, ba); issue_w(80);
        WAITVM(12); tapc(77 & 3, 5, ba);
        WAITVM(8);  tapc(78 & 3, 6, ba);
        WAITVM(4);  tapc(79 & 3, 7, ba);
        WAITVM(0);  tapc(80 & 3, 8, ba);
    }

    // epilogue: GELU -> bf16 -> swizzled h1pad cell (interior)
    u16* hcell = h1pad + HB + b * HSTR + ((l + 1) * (P + 2) + (q + 1)) * 6400;
#pragma unroll
    for (int mt = 0; mt < 4; ++mt)
#pragma unroll
        for (int r = 0; r < 4; ++r) {
            int pos = mt * 16 + quad * 4 + r;
            int cellpos = ((pos >> 3) + 1) * 10 + (pos & 7) + 1;
#pragma unroll
            for (int nt = 0; nt < 4; ++nt) {
                int o = nt * 16 + m;
                hcell[cellpos * 64 + (((o >> 3) ^ (cellpos & 7)) << 3) + (o & 7)] =
                    f2bf(gelu_exact(acc[mt][nt][r]));
            }
        }
}

__global__ __launch_bounds__(64) void conv1_k(
    const u16* __restrict__ ws_x, const u16* __restrict__ ws_w1,
    u16* __restrict__ ws_h1) {
    __shared__ __align__(16) u16 s_w[4 * 2048];   // 16 KB weight ring
    __shared__ __align__(16) u16 s_a[2 * 3584];   // 14 KB act dbuf -> 30 KB
    int g = blockIdx.x;
    int jid = (g & 7) * 72 + (g >> 3);            // XCD-chunked, 576 = 8*72
    int per = jid / 192; int bt = jid - per * 192;
    if (per == 0)      conv1_body<2>(ws_x, ws_w1, ws_h1, bt, s_w, s_a);
    else if (per == 1) conv1_body<3>(ws_x, ws_w1, ws_h1, bt, s_w, s_a);
    else               conv1_body<4>(ws_x, ws_w1, ws_h1, bt, s_w, s_a);
}

// ---- conv2 (C64->C32). 1 wave = one t, all 32 o, K=64. ----
template<int P>
__device__ __forceinline__ void conv2_body(
    const u16* __restrict__ h1pad, const u16* __restrict__ w2b,
    float* __restrict__ h2per, int bt,
    u16* __restrict__ s_w, u16* __restrict__ s_a) {
    constexpr int L = 48 / P;
    constexpr int HB = (P == 2) ? HB0 : (P == 3) ? HB1 : HB2;
    constexpr int HSTR = (L + 2) * (P + 2) * 6400;

    int lane = threadIdx.x;
    int m = lane & 15, quad = lane >> 4;
    int b = bt / 48, t = bt - b * 48;
    int l = t / P, q = t - l * P;

    const u16* hc = h1pad + HB + b * HSTR + (l * (P + 2) + q) * 6400;

    int sp[4];
#pragma unroll
    for (int mt = 0; mt < 4; ++mt) {
        int pos = mt * 16 + m;
        sp[mt] = (pos >> 3) * 10 + (pos & 7);
    }

    f32x4 acc[4][2];
#pragma unroll
    for (int mt = 0; mt < 4; ++mt)
#pragma unroll
        for (int nt = 0; nt < 2; ++nt) acc[mt][nt] = f32x4{0.f, 0.f, 0.f, 0.f};

    auto issue_w = [&](int Tt) {
        const u16* src = w2b + Tt * 2048;
        u16* dst = s_w + (Tt & 3) * 2048;
#pragma unroll
        for (int i = 0; i < 4; ++i) cp1k(src + i * 512, dst + i * 512, lane);
    };
    auto issue_a = [&](int gg) {
        const u16* src = hc + ((gg / 3) * (P + 2) + (gg % 3)) * 6400;
        u16* dst = s_a + (gg & 1) * 6656;
#pragma unroll
        for (int i = 0; i < 13; ++i) cp1k(src + i * 512, dst + i * 512, lane);
    };
    auto tapc = [&](int slot, int dwh, const u16* ba) {
        int dw = dwh / 3, dh = dwh - (dwh / 3) * 3;
        const u16* bw = s_w + slot * 2048;
        bf16x8 wf[2][2];   // [nt][ks]
#pragma unroll
        for (int nt = 0; nt < 2; ++nt)
#pragma unroll
            for (int ks = 0; ks < 2; ++ks)
                wf[nt][ks] = *(const bf16x8*)(bw +
                    ((((ks * 4 + quad) * 2 + nt) * 16 + m) << 3));
        bf16x8 af[4][2];   // [mt][ks]
#pragma unroll
        for (int mt = 0; mt < 4; ++mt) {
            int cellpos = sp[mt] + dw * 10 + dh;
#pragma unroll
            for (int ks = 0; ks < 2; ++ks)
                af[mt][ks] = *(const bf16x8*)(ba + cellpos * 64 +
                    (((ks * 4 + quad) ^ (cellpos & 7)) << 3));
        }
#pragma unroll
        for (int mt = 0; mt < 4; ++mt)
#pragma unroll
            for (int ks = 0; ks < 2; ++ks)
#pragma unroll
                for (int nt = 0; nt < 2; ++nt)
                    acc[mt][nt] = __builtin_amdgcn_mfma_f32_16x16x32_bf16(
                        af[mt][ks], wf[nt][ks], acc[mt][nt], 0, 0, 0);
    };

    issue_a(0);
    issue_w(0); issue_w(1); issue_w(2); issue_w(3);

#pragma unroll 1
    for (int g = 0; g < 8; ++g) {
        issue_a(g + 1);
        int T0 = g * 9;
        const u16* ba = s_a + (g & 1) * 6656;
        WAITVM(25); tapc((T0 + 0) & 3, 0, ba); issue_w(T0 + 4);
        WAITVM(25); tapc((T0 + 1) & 3, 1, ba); issue_w(T0 + 5);
        WAITVM(25); tapc((T0 + 2) & 3, 2, ba); issue_w(T0 + 6);
        WAITVM(25); tapc((T0 + 3) & 3, 3, ba); issue_w(T0 + 7);
        WAITVM(12); tapc((T0 + 4) & 3, 4, ba); issue_w(T0 + 8);
        WAITVM(12); tapc((T0 + 5) & 3, 5, ba); issue_w(T0 + 9);
        WAITVM(12); tapc((T0 + 6) & 3, 6, ba); issue_w(T0 + 10);
        WAITVM(12); tapc((T0 + 7) & 3, 7, ba); issue_w(T0 + 11);
        WAITVM(12); tapc((T0 + 8) & 3, 8, ba); issue_w(T0 + 12);
    }
    {   // tail group g=8
        const u16* ba = s_a;
        WAITVM(12); tapc(72 & 3, 0, ba); issue_w(76);
        WAITVM(12); tapc(73 & 3, 1, ba); issue_w(77);
        WAITVM(12); tapc(74 & 3, 2, ba); issue_w(78);
        WAITVM(12); tapc(75 & 3, 3, ba); issue_w(79);
        WAITVM(12); tapc(76 & 3, 4, ba); issue_w(80);
        WAITVM(12); tapc(77 & 3, 5, ba);
        WAITVM(8);  tapc(78 & 3, 6, ba);
        WAITVM(4);  tapc(79 & 3, 7, ba);
        WAITVM(0);  tapc(80 & 3, 8, ba);
    }

    float* orow = h2per + (b * 48 + t) * 2048;
#pragma unroll
    for (int mt = 0; mt < 4; ++mt)
#pragma unroll
        for (int nt = 0; nt < 2; ++nt)
#pragma unroll
            for (int r = 0; r < 4; ++r) {
                int pos = mt * 16 + quad * 4 + r;
                orow[pos * 32 + nt * 16 + m] = acc[mt][nt][r];
            }
}

__global__ __launch_bounds__(64) void conv2_k(
    const u16* __restrict__ ws_h1, const u16* __restrict__ ws_w2,
    float* __restrict__ h2) {
    __shared__ __align__(16) u16 s_w[4 * 2048];   // 16 KB weight ring
    __shared__ __align__(16) u16 s_a[2 * 6656];   // 26 KB act dbuf -> 43 KB
    int g = blockIdx.x;
    int jid = (g & 7) * 72 + (g >> 3);            // same XCD mapping as conv1
    int per = jid / 192; int bt = jid - per * 192;
    float* h2per = h2 + per * H2_PER;
    if (per == 0)      conv2_body<2>(ws_h1, ws_w2, h2per, bt, s_w, s_a);
    else if (per == 1) conv2_body<3>(ws_h1, ws_w2, h2per, bt, s_w, s_a);
    else               conv2_body<4>(ws_h1, ws_w2, h2per, bt, s_w, s_a);
}

// ---- out = x + (h2_p0 + h2_p1 + h2_p2) / 3 ----
__global__ __launch_bounds__(256) void final_add(
    const float* __restrict__ x, const float* __restrict__ h2,
    float* __restrict__ out) {
    int i = blockIdx.x * 256 + threadIdx.x;
    float4 xv = ((const float4*)x)[i];
    float4 a = ((const float4*)h2)[i];
    float4 bv = ((const float4*)(h2 + H2_PER))[i];
    float4 cv = ((const float4*)(h2 + 2 * H2_PER))[i];
    const float s = 1.0f / 3.0f;
    float4 o;
    o.x = xv.x + (a.x + bv.x + cv.x) * s;
    o.y = xv.y + (a.y + bv.y + cv.y) * s;
    o.z = xv.z + (a.z + bv.z + cv.z) * s;
    o.w = xv.w + (a.w + bv.w + cv.w) * s;
    ((float4*)out)[i] = o;
}

extern "C" void kernel_launch(void* const* d_in, const int* in_sizes, int n_in,
                              void* d_out, int out_size, void* d_ws, size_t ws_size,
                              hipStream_t stream) {
    const float* x    = (const float*)d_in[0];
    const float* w1_0 = (const float*)d_in[1];
    const float* w1_1 = (const float*)d_in[2];
    const float* w2_0 = (const float*)d_in[3];
    const float* w2_1 = (const float*)d_in[4];
    float* out = (float*)d_out;

    u16* ws = (u16*)d_ws;
    u16* ws_x  = ws;
    u16* ws_w1 = ws + W1OFF;
    u16* ws_w2 = ws + W2OFF;
    u16* ws_h1 = ws + H1OFF;
    float* h2  = (float*)(ws + H2OFF_U16);

    (void)hipMemsetAsync(ws_h1, 0, (size_t)H1TOT * 2, stream);
    prep<<<PREP_N / 256, 256, 0, stream>>>(x, w1_0, w1_1, w2_0, w2_1, ws);
    conv1_k<<<576, 64, 0, stream>>>(ws_x, ws_w1, ws_h1);
    conv2_k<<<576, 64, 0, stream>>>(ws_h1, ws_w2, h2);
    final_add<<<H2_PER / 4 / 256, 256, 0, stream>>>(x, h2, out);
}

// Round 10
// 145.913 us; speedup vs baseline: 1.2068x; 1.1445x over previous
//
#include <hip/hip_runtime.h>
#include <math.h>

// B=4, T=48, W=8, H=8, C=32; d_ff=64; periods {2,3,4}. T%P==0 always.
// (1x1 + 3^4)/2 inception folded into one 81-tap conv (center tap 40).
// Padded in L,P,W,H -> branch-free 81 taps.
// R10: 4-wave blocks (2 t-cells x 2 halves) sharing block-staged weights,
// 3-tap double-buffered chunks, issue-after-barrier pipeline (the barrier's
// implicit vmcnt drain is the wait; one-chunk prefetch window). 1152 waves
// per conv (2x R9), weight DMA halved.

typedef __attribute__((ext_vector_type(8))) short bf16x8;
typedef __attribute__((ext_vector_type(4))) float f32x4;
typedef unsigned short u16;

#define XB0 0
#define XB1 1331200            // 4 * 26*4*3200
#define XB2 2483200            // XB1 + 4 * 18*5*3200
#define XTOT 3558400           // XB2 + 4 * 14*6*3200
#define W1OFF XTOT             // 165888 bf16: [tap 0..80][2048]
#define W2OFF (XTOT + 165888)  // 165888 bf16: [tap 0..80][2048]
#define H1OFF (XTOT + 331776)  // h1pad3 (C=64, swizzled cells)
#define HB0 0
#define HB1 2662400            // 4 * 26*4*6400
#define HB2 4966400            // HB1 + 4 * 18*5*6400
#define H1TOT 7116800
#define H2OFF_U16 (H1OFF + H1TOT)
#define H2_PER 393216          // fp32 per period: 192*64*32
#define PREP_N (XTOT + 331776)

__device__ __forceinline__ u16 f2bf(float f) {
    unsigned u = __float_as_uint(f);
    unsigned r = u + 0x7fffu + ((u >> 16) & 1u);
    return (u16)(r >> 16);
}
__device__ __forceinline__ float gelu_exact(float v) {
    return 0.5f * v * (1.0f + erff(v * 0.7071067811865476f));
}

// async copy of 1 KB: 64 lanes x 16 B. LDS dest = wave-uniform base + lane*16.
__device__ __forceinline__ void cp1k(const u16* g, u16* l, int lane) {
    __builtin_amdgcn_global_load_lds(
        (const __attribute__((address_space(1))) unsigned int*)(g + lane * 8),
        (__attribute__((address_space(3))) unsigned int*)(l + lane * 8),
        16, 0, 0);
}

// ---- prep (unchanged layouts from R9) ----
template<int P>
__device__ __forceinline__ void prep_x(const float* __restrict__ x,
                                       u16* __restrict__ dst, int j) {
    constexpr int L = 48 / P;
    constexpr int SZ = (L + 2) * (P + 2) * 3200;
    int b = j / SZ; int r = j - b * SZ;
    int cell2d = r / 3200; int inner = r - cell2d * 3200;
    int cellpos = inner >> 5; int low = inner & 31;
    int sc = low >> 3, jj = low & 7;
    int c = ((sc ^ (cellpos & 3)) << 3) + jj;
    int wp = cellpos / 10, hp = cellpos - (cellpos / 10) * 10;
    int qp = cell2d % (P + 2), lp = cell2d / (P + 2);
    float v = 0.f;
    if (lp >= 1 && lp <= L && qp >= 1 && qp <= P &&
        wp >= 1 && wp <= 8 && hp >= 1 && hp <= 8) {
        int t = (lp - 1) * P + (qp - 1);
        v = x[((b * 48 + t) * 64 + (wp - 1) * 8 + (hp - 1)) * 32 + c];
    }
    dst[j] = f2bf(v);
}

__global__ __launch_bounds__(256) void prep(
    const float* __restrict__ x,
    const float* __restrict__ w1_0, const float* __restrict__ w1_1,
    const float* __restrict__ w2_0, const float* __restrict__ w2_1,
    u16* __restrict__ ws) {
    int i = blockIdx.x * 256 + threadIdx.x;
    if (i < XB1) {
        prep_x<2>(x, ws + XB0, i - XB0);
    } else if (i < XB2) {
        prep_x<3>(x, ws + XB1, i - XB1);
    } else if (i < XTOT) {
        prep_x<4>(x, ws + XB2, i - XB2);
    } else if (i < W2OFF) {
        // w1: [tap][chunk(256)*8+jj], chunk = (quad*4+nt4)*16+m
        int j = i - W1OFF;
        int tap = j >> 11; int r = j & 2047;
        int chunk = r >> 3, jj = r & 7;
        int m = chunk & 15, nt = (chunk >> 4) & 3, quad = chunk >> 6;
        int o = nt * 16 + m, c = quad * 8 + jj;
        float v = 0.5f * w1_1[(o * 32 + c) * 81 + tap];
        if (tap == 40) v += 0.5f * w1_0[o * 32 + c];
        ws[i] = f2bf(v);
    } else if (i < PREP_N) {
        // w2: [tap][chunk(256)*8+jj], chunk = ((ks*4+quad)*2+nt)*16+m
        int j = i - W2OFF;
        int tap = j >> 11; int r = j & 2047;
        int chunk = r >> 3, jj = r & 7;
        int m = chunk & 15, nt = (chunk >> 4) & 1;
        int quad = (chunk >> 5) & 3, ks = chunk >> 7;
        int o = nt * 16 + m, c = ks * 32 + quad * 8 + jj;
        float v = 0.5f * w2_1[(o * 64 + c) * 81 + tap];
        if (tap == 40) v += 0.5f * w2_0[o * 64 + c];
        ws[i] = f2bf(v);
    }
}

// ---- conv1 (C32->C64) + GELU. Block = 4 waves: (tloc, nh) = (wv>>1, wv&1).
// Wave: M=64 (its t), N=32 (its o-half). Weights shared block-wide. ----
template<int P>
__device__ __forceinline__ void conv1_body(
    const u16* __restrict__ xpad, const u16* __restrict__ w1b,
    u16* __restrict__ h1pad, int tp, int bb,
    u16* __restrict__ s_w, u16* __restrict__ s_a) {
    constexpr int L = 48 / P;
    constexpr int XB = (P == 2) ? XB0 : (P == 3) ? XB1 : XB2;
    constexpr int HB = (P == 2) ? HB0 : (P == 3) ? HB1 : HB2;
    constexpr int XSTR = (L + 2) * (P + 2) * 3200;
    constexpr int HSTR = (L + 2) * (P + 2) * 6400;

    int tid = threadIdx.x;
    int lane = tid & 63, wv = tid >> 6;
    int m = lane & 15, quad = lane >> 4;
    int tloc = wv >> 1, nh = wv & 1;

    const u16* xcs[2];
#pragma unroll
    for (int c2 = 0; c2 < 2; ++c2) {
        int tt = tp * 2 + c2;
        int ll = tt / P, qq = tt - ll * P;
        xcs[c2] = xpad + XB + bb * XSTR + (ll * (P + 2) + qq) * 3200;
    }

    int sp[4];
#pragma unroll
    for (int mt = 0; mt < 4; ++mt) {
        int pos = mt * 16 + m;
        sp[mt] = (pos >> 3) * 10 + (pos & 7);
    }

    f32x4 acc[4][2];
#pragma unroll
    for (int mt = 0; mt < 4; ++mt)
#pragma unroll
        for (int nt = 0; nt < 2; ++nt) acc[mt][nt] = f32x4{0.f, 0.f, 0.f, 0.f};

    // stage chunk cgn's weights (taps 3cgn..3cgn+2, 12 KB): wave takes 3 pieces
    auto stageW = [&](int cgn) {
        const u16* src = w1b + (cgn * 3) * 2048;
        u16* dst = s_w + (cgn & 1) * 6144;
        int p0 = wv * 3;
#pragma unroll
        for (int i = 0; i < 3; ++i)
            cp1k(src + (p0 + i) * 512, dst + (p0 + i) * 512, lane);
    };
    // stage piece range [k0,k1) of group gg's act cells (14 pieces: 7/cell)
    auto stageA = [&](int gg, int k0, int k1) {
        int coff = ((gg / 3) * (P + 2) + (gg % 3)) * 3200;
        for (int k = k0 + wv; k < k1; k += 4) {
            int cell = k / 7, pc = k - (k / 7) * 7;
            cp1k(xcs[cell] + coff + pc * 512,
                 s_a + (cell * 2 + (gg & 1)) * 3584 + pc * 512, lane);
        }
    };

    stageW(0);
    stageA(0, 0, 14);

#pragma unroll 1
    for (int cg = 0; cg < 27; ++cg) {
        __syncthreads();   // implicit vmcnt(0): cg's data delivered; all waves
                           // done with chunk cg-1 -> safe to overwrite buffers
        if (cg < 26) stageW(cg + 1);
        int grp = cg / 3, part = cg - grp * 3;
        if (grp < 8) stageA(grp + 1, part * 5, (part == 2) ? 14 : part * 5 + 5);

        const u16* bw = s_w + (cg & 1) * 6144;
        const u16* ba = s_a + (tloc * 2 + (grp & 1)) * 3584;
        int dwb = part * 10;   // dw = part
#pragma unroll
        for (int j = 0; j < 3; ++j) {
            const u16* tw = bw + j * 2048;
            bf16x8 wf[2];
#pragma unroll
            for (int nt = 0; nt < 2; ++nt)
                wf[nt] = *(const bf16x8*)(tw +
                    (((quad * 4 + nh * 2 + nt) * 16 + m) << 3));
            bf16x8 af[4];
#pragma unroll
            for (int mt = 0; mt < 4; ++mt) {
                int cellpos = sp[mt] + dwb + j;
                af[mt] = *(const bf16x8*)(ba + cellpos * 32 +
                                          ((quad ^ (cellpos & 3)) << 3));
            }
#pragma unroll
            for (int mt = 0; mt < 4; ++mt)
#pragma unroll
                for (int nt = 0; nt < 2; ++nt)
                    acc[mt][nt] = __builtin_amdgcn_mfma_f32_16x16x32_bf16(
                        af[mt], wf[nt], acc[mt][nt], 0, 0, 0);
        }
    }

    // epilogue: GELU -> bf16 -> swizzled h1pad cell (own t, own o-half)
    int t = tp * 2 + tloc;
    int l = t / P, q = t - l * P;
    u16* hcell = h1pad + HB + bb * HSTR + ((l + 1) * (P + 2) + (q + 1)) * 6400;
#pragma unroll
    for (int mt = 0; mt < 4; ++mt)
#pragma unroll
        for (int r = 0; r < 4; ++r) {
            int pos = mt * 16 + quad * 4 + r;
            int cellpos = ((pos >> 3) + 1) * 10 + (pos & 7) + 1;
#pragma unroll
            for (int nt = 0; nt < 2; ++nt) {
                int o = nh * 32 + nt * 16 + m;
                hcell[cellpos * 64 + (((o >> 3) ^ (cellpos & 7)) << 3) + (o & 7)] =
                    f2bf(gelu_exact(acc[mt][nt][r]));
            }
        }
}

__global__ __launch_bounds__(256) void conv1_k(
    const u16* __restrict__ ws_x, const u16* __restrict__ ws_w1,
    u16* __restrict__ ws_h1) {
    __shared__ __align__(16) u16 s_w[2 * 6144];   // 24 KB weight dbuf
    __shared__ __align__(16) u16 s_a[4 * 3584];   // 28 KB act [cell][dbuf]
    int g = blockIdx.x;
    int jid = (g & 7) * 36 + (g >> 3);            // XCD-chunked, 288 = 8*36
    int per = jid / 96; int rem = jid - per * 96;
    int bb = rem / 24; int tp = rem - bb * 24;
    if (per == 0)      conv1_body<2>(ws_x, ws_w1, ws_h1, tp, bb, s_w, s_a);
    else if (per == 1) conv1_body<3>(ws_x, ws_w1, ws_h1, tp, bb, s_w, s_a);
    else               conv1_body<4>(ws_x, ws_w1, ws_h1, tp, bb, s_w, s_a);
}

// ---- conv2 (C64->C32). Block = 4 waves: (tloc, mh) = (wv>>1, wv&1).
// Wave: M=32 (its pos-half), N=32 (all o), K=64. ----
template<int P>
__device__ __forceinline__ void conv2_body(
    const u16* __restrict__ h1pad, const u16* __restrict__ w2b,
    float* __restrict__ h2per, int tp, int bb,
    u16* __restrict__ s_w, u16* __restrict__ s_a) {
    constexpr int L = 48 / P;
    constexpr int HB = (P == 2) ? HB0 : (P == 3) ? HB1 : HB2;
    constexpr int HSTR = (L + 2) * (P + 2) * 6400;

    int tid = threadIdx.x;
    int lane = tid & 63, wv = tid >> 6;
    int m = lane & 15, quad = lane >> 4;
    int tloc = wv >> 1, mh = wv & 1;

    const u16* hcs[2];
#pragma unroll
    for (int c2 = 0; c2 < 2; ++c2) {
        int tt = tp * 2 + c2;
        int ll = tt / P, qq = tt - ll * P;
        hcs[c2] = h1pad + HB + bb * HSTR + (ll * (P + 2) + qq) * 6400;
    }

    int sp[2];
#pragma unroll
    for (int mt = 0; mt < 2; ++mt) {
        int pos = mh * 32 + mt * 16 + m;
        sp[mt] = (pos >> 3) * 10 + (pos & 7);
    }

    f32x4 acc[2][2];
#pragma unroll
    for (int mt = 0; mt < 2; ++mt)
#pragma unroll
        for (int nt = 0; nt < 2; ++nt) acc[mt][nt] = f32x4{0.f, 0.f, 0.f, 0.f};

    auto stageW = [&](int cgn) {
        const u16* src = w2b + (cgn * 3) * 2048;
        u16* dst = s_w + (cgn & 1) * 6144;
        int p0 = wv * 3;
#pragma unroll
        for (int i = 0; i < 3; ++i)
            cp1k(src + (p0 + i) * 512, dst + (p0 + i) * 512, lane);
    };
    // 26 pieces: 13/cell (cell 6400 u16 + 256 overread into 6656 slot)
    auto stageA = [&](int gg, int k0, int k1) {
        int coff = ((gg / 3) * (P + 2) + (gg % 3)) * 6400;
        for (int k = k0 + wv; k < k1; k += 4) {
            int cell = k / 13, pc = k - (k / 13) * 13;
            cp1k(hcs[cell] + coff + pc * 512,
                 s_a + (cell * 2 + (gg & 1)) * 6656 + pc * 512, lane);
        }
    };

    stageW(0);
    stageA(0, 0, 26);

#pragma unroll 1
    for (int cg = 0; cg < 27; ++cg) {
        __syncthreads();
        if (cg < 26) stageW(cg + 1);
        int grp = cg / 3, part = cg - grp * 3;
        if (grp < 8) stageA(grp + 1, part * 9, (part == 2) ? 26 : part * 9 + 9);

        const u16* bw = s_w + (cg & 1) * 6144;
        const u16* ba = s_a + (tloc * 2 + (grp & 1)) * 6656;
        int dwb = part * 10;
#pragma unroll
        for (int j = 0; j < 3; ++j) {
            const u16* tw = bw + j * 2048;
            bf16x8 wf[2][2];   // [nt][ks]
#pragma unroll
            for (int nt = 0; nt < 2; ++nt)
#pragma unroll
                for (int ks = 0; ks < 2; ++ks)
                    wf[nt][ks] = *(const bf16x8*)(tw +
                        ((((ks * 4 + quad) * 2 + nt) * 16 + m) << 3));
            bf16x8 af[2][2];   // [mt][ks]
#pragma unroll
            for (int mt = 0; mt < 2; ++mt) {
                int cellpos = sp[mt] + dwb + j;
#pragma unroll
                for (int ks = 0; ks < 2; ++ks)
                    af[mt][ks] = *(const bf16x8*)(ba + cellpos * 64 +
                        (((ks * 4 + quad) ^ (cellpos & 7)) << 3));
            }
#pragma unroll
            for (int mt = 0; mt < 2; ++mt)
#pragma unroll
                for (int ks = 0; ks < 2; ++ks)
#pragma unroll
                    for (int nt = 0; nt < 2; ++nt)
                        acc[mt][nt] = __builtin_amdgcn_mfma_f32_16x16x32_bf16(
                            af[mt][ks], wf[nt][ks], acc[mt][nt], 0, 0, 0);
        }
    }

    int t = tp * 2 + tloc;
    float* orow = h2per + (bb * 48 + t) * 2048;
#pragma unroll
    for (int mt = 0; mt < 2; ++mt)
#pragma unroll
        for (int nt = 0; nt < 2; ++nt)
#pragma unroll
            for (int r = 0; r < 4; ++r) {
                int pos = mh * 32 + mt * 16 + quad * 4 + r;
                orow[pos * 32 + nt * 16 + m] = acc[mt][nt][r];
            }
}

__global__ __launch_bounds__(256) void conv2_k(
    const u16* __restrict__ ws_h1, const u16* __restrict__ ws_w2,
    float* __restrict__ h2) {
    __shared__ __align__(16) u16 s_w[2 * 6144];   // 24 KB
    __shared__ __align__(16) u16 s_a[4 * 6656];   // 52 KB -> 76 KB total
    int g = blockIdx.x;
    int jid = (g & 7) * 36 + (g >> 3);            // same XCD mapping as conv1
    int per = jid / 96; int rem = jid - per * 96;
    int bb = rem / 24; int tp = rem - bb * 24;
    float* h2per = h2 + per * H2_PER;
    if (per == 0)      conv2_body<2>(ws_h1, ws_w2, h2per, tp, bb, s_w, s_a);
    else if (per == 1) conv2_body<3>(ws_h1, ws_w2, h2per, tp, bb, s_w, s_a);
    else               conv2_body<4>(ws_h1, ws_w2, h2per, tp, bb, s_w, s_a);
}

// ---- out = x + (h2_p0 + h2_p1 + h2_p2) / 3 ----
__global__ __launch_bounds__(256) void final_add(
    const float* __restrict__ x, const float* __restrict__ h2,
    float* __restrict__ out) {
    int i = blockIdx.x * 256 + threadIdx.x;
    float4 xv = ((const float4*)x)[i];
    float4 a = ((const float4*)h2)[i];
    float4 bv = ((const float4*)(h2 + H2_PER))[i];
    float4 cv = ((const float4*)(h2 + 2 * H2_PER))[i];
    const float s = 1.0f / 3.0f;
    float4 o;
    o.x = xv.x + (a.x + bv.x + cv.x) * s;
    o.y = xv.y + (a.y + bv.y + cv.y) * s;
    o.z = xv.z + (a.z + bv.z + cv.z) * s;
    o.w = xv.w + (a.w + bv.w + cv.w) * s;
    ((float4*)out)[i] = o;
}

extern "C" void kernel_launch(void* const* d_in, const int* in_sizes, int n_in,
                              void* d_out, int out_size, void* d_ws, size_t ws_size,
                              hipStream_t stream) {
    const float* x    = (const float*)d_in[0];
    const float* w1_0 = (const float*)d_in[1];
    const float* w1_1 = (const float*)d_in[2];
    const float* w2_0 = (const float*)d_in[3];
    const float* w2_1 = (const float*)d_in[4];
    float* out = (float*)d_out;

    u16* ws = (u16*)d_ws;
    u16* ws_x  = ws;
    u16* ws_w1 = ws + W1OFF;
    u16* ws_w2 = ws + W2OFF;
    u16* ws_h1 = ws + H1OFF;
    float* h2  = (float*)(ws + H2OFF_U16);

    (void)hipMemsetAsync(ws_h1, 0, (size_t)H1TOT * 2, stream);
    prep<<<PREP_N / 256, 256, 0, stream>>>(x, w1_0, w1_1, w2_0, w2_1, ws);
    conv1_k<<<288, 256, 0, stream>>>(ws_x, ws_w1, ws_h1);
    conv2_k<<<288, 256, 0, stream>>>(ws_h1, ws_w2, h2);
    final_add<<<H2_PER / 4 / 256, 256, 0, stream>>>(x, h2, out);
}